// Round 4
// baseline (177.458 us; speedup 1.0000x reference)
//
#include <hip/hip_runtime.h>
#include <math.h>

#define TPB 256
#define WPW (TPB / 64)        // waves per workgroup
#define NBLOCKS 1024          // 4096 waves, ~7.6 tiles/wave at B=2M

// R = (1 - b*th2) I + b * v v^T + a * K, K = skew(v).
// Fast-math: rsqrt + native sin/cos (validated: absmax 0.0625 << 2.3 threshold).
__device__ __forceinline__ void rodrigues(float v0, float v1, float v2, float R[9]) {
    float th2 = v0 * v0 + v1 * v1 + v2 * v2;
    bool  sm  = th2 < 1e-12f;            // th < 1e-6
    float g   = sm ? 1.0f : th2;
    float inv = rsqrtf(g);
    float th  = g * inv;                 // sqrt(g)
    float s   = __sinf(th);
    float c   = __cosf(th);
    float a   = sm ? 1.0f : s * inv;
    float b   = sm ? 0.5f : (1.0f - c) * (inv * inv);
    float cc  = 1.0f - b * th2;
    R[0] = cc + b * v0 * v0;      R[1] = b * v0 * v1 - a * v2;  R[2] = b * v0 * v2 + a * v1;
    R[3] = b * v0 * v1 + a * v2;  R[4] = cc + b * v1 * v1;      R[5] = b * v1 * v2 - a * v0;
    R[6] = b * v0 * v2 - a * v1;  R[7] = b * v1 * v2 + a * v0;  R[8] = cc + b * v2 * v2;
}

__device__ __forceinline__ void load12(const float* __restrict__ trans,
                                       const float* __restrict__ rotat,
                                       const float* __restrict__ sdir,
                                       const float* __restrict__ scal,
                                       int b3, float p[12]) {
    p[0] = trans[b3]; p[1]  = trans[b3+1]; p[2]  = trans[b3+2];
    p[3] = rotat[b3]; p[4]  = rotat[b3+1]; p[5]  = rotat[b3+2];
    p[6] = sdir [b3]; p[7]  = sdir [b3+1]; p[8]  = sdir [b3+2];
    p[9] = scal [b3]; p[10] = scal [b3+1]; p[11] = scal [b3+2];
}

__global__ __launch_bounds__(TPB) void aff_kernel(
    const float* __restrict__ trans,
    const float* __restrict__ rotat,
    const float* __restrict__ sdir,
    const float* __restrict__ scal,
    float4* __restrict__ out,
    int T)                               // tiles of 64 elements (B/64)
{
    __shared__ float4 s_out[WPW][192];   // 3 KB per wave, wave-private
    const int w   = threadIdx.x >> 6;
    const int l   = threadIdx.x & 63;
    float4* slab  = s_out[w];
    const int wid = blockIdx.x * WPW + w;
    const int W   = gridDim.x * WPW;     // total waves

    int t = wid;
    if (t >= T) return;

    // ---- pipeline prologue: prefetch first tile ----
    float p[12];
    load12(trans, rotat, sdir, scal, 3 * ((t << 6) + l), p);

    while (true) {
        // rotate prefetch regs into current (vmcnt wait lands here — the loads
        // for this tile were issued a full iteration ago)
        float c[12];
#pragma unroll
        for (int i = 0; i < 12; ++i) c[i] = p[i];

        // ---- issue next tile's loads BEFORE compute (latency hidden by ILP) ----
        const int tn = t + W;
        if (tn < T) load12(trans, rotat, sdir, scal, 3 * ((tn << 6) + l), p);

        // ---- compute ----
        float R[9], U[9];
        rodrigues(c[3], c[4], c[5], R);
        rodrigues(c[6], c[7], c[8], U);
        float d0 = __expf(c[9]);
        float d1 = __expf(c[10]);
        float d2 = __expf(c[11]);

        float Wm[9];                     // W = U * diag(d)
#pragma unroll
        for (int i = 0; i < 3; ++i) {
            Wm[3*i+0] = U[3*i+0] * d0;
            Wm[3*i+1] = U[3*i+1] * d1;
            Wm[3*i+2] = U[3*i+2] * d2;
        }
        float S[9];                      // S = W * U^T
#pragma unroll
        for (int i = 0; i < 3; ++i)
#pragma unroll
            for (int j = 0; j < 3; ++j)
                S[3*i+j] = Wm[3*i+0]*U[3*j+0] + Wm[3*i+1]*U[3*j+1] + Wm[3*i+2]*U[3*j+2];
        float M[9];                      // M = R * S
#pragma unroll
        for (int i = 0; i < 3; ++i)
#pragma unroll
            for (int j = 0; j < 3; ++j)
                M[3*i+j] = R[3*i+0]*S[0+j] + R[3*i+1]*S[3+j] + R[3*i+2]*S[6+j];

        // ---- wave-local LDS transpose -> 3 coalesced 1 KB stores ----
        slab[3*l + 0] = make_float4(M[0], M[1], M[2], c[0]);
        slab[3*l + 1] = make_float4(M[3], M[4], M[5], c[1]);
        slab[3*l + 2] = make_float4(M[6], M[7], M[8], c[2]);
        __builtin_amdgcn_wave_barrier(); // reorder fence; wave64 lockstep, DS in-order

        const int ob = 192 * t;          // this tile's float4 base in out
#pragma unroll
        for (int k = 0; k < 3; ++k) {
            int idx = (k << 6) + l;
            out[ob + idx] = slab[idx];
        }

        if (tn >= T) break;
        t = tn;
    }
}

extern "C" void kernel_launch(void* const* d_in, const int* in_sizes, int n_in,
                              void* d_out, int out_size, void* d_ws, size_t ws_size,
                              hipStream_t stream) {
    const float* tr = (const float*)d_in[0];
    const float* ro = (const float*)d_in[1];
    const float* sd = (const float*)d_in[2];
    const float* sc = (const float*)d_in[3];
    float4* out = (float4*)d_out;

    int B = in_sizes[0] / 3;             // 2,000,000 elements (divisible by 64)
    int T = B >> 6;                      // 31,250 tiles
    int blocks = NBLOCKS;
    if (blocks * WPW > T) blocks = (T + WPW - 1) / WPW;
    aff_kernel<<<blocks, TPB, 0, stream>>>(tr, ro, sd, sc, out, T);
}